// Round 14
// baseline (474.670 us; speedup 1.0000x reference)
//
#include <hip/hip_runtime.h>

#define SEQ 512
#define BATCH 8192
#define LOG2E  1.44269504088896340736f
#define LOG2E2 2.88539008177792681472f   // 2*log2(e)

typedef _Float16 f16x8 __attribute__((ext_vector_type(8)));
typedef float    f32x4 __attribute__((ext_vector_type(4)));
typedef unsigned u32x4 __attribute__((ext_vector_type(4)));

__device__ __forceinline__ float fexp2(float x) { return __builtin_amdgcn_exp2f(x); }
__device__ __forceinline__ float frcp(float x)  { return __builtin_amdgcn_rcpf(x); }
__device__ __forceinline__ unsigned pkf16(_Float16 a, _Float16 b) {
    return (unsigned)__builtin_bit_cast(unsigned short, a) |
           ((unsigned)__builtin_bit_cast(unsigned short, b) << 16);
}

// MFMA LSTM, DUAL-GROUP interleave: one wave carries TWO independent
// 16-element batch groups (A: Eb..Eb+15, B: Eb+16..Eb+31). Their per-step
// dependency chains are independent, so group B's MFMAs + activation issue
// inside group A's stall slots (r9-r13 showed ~50% of each step is exposed
// latency at 1 indep chain/wave). A-fragments and bias are SHARED — only
// B-state/c/h/x-prefetch duplicate.
// Per-group step = r13's lean path (verified absmax 4.9e-4):
//   z(80) = W_hi·v + W_lo·v + bias, 5 tiles x 2 chained mfma 16x16x32_f16;
//   v = [x_hi; h1; h2; x_lo] all-register (pair P=4T+q at k=8q+2+T; x_hi at
//   k=0,1; x_lo at k=7,15 with duplicated w_ih0 cols). Producer lane ==
//   consumer lane -> recurrence never leaves registers.
__global__ __launch_bounds__(64) void lstm2_fc_mfma(
    const float* __restrict__ x,
    const float* __restrict__ w_ih0, const float* __restrict__ w_hh0,
    const float* __restrict__ b_ih0, const float* __restrict__ b_hh0,
    const float* __restrict__ w_ih1, const float* __restrict__ w_hh1,
    const float* __restrict__ b_ih1, const float* __restrict__ b_hh1,
    const float* __restrict__ fc_w, const float* __restrict__ fc_b,
    float* __restrict__ out)
{
    __shared__ float hfc[32][10];

    const int lane = threadIdx.x;
    const int e    = lane & 15;      // elem column / A-row-in-tile
    const int q    = lane >> 4;      // K-chunk for A/B; row-quad for C/D
    const int Eb   = blockIdx.x * 32;
    const bool qz  = (q == 0);

    // ---- shared A fragments hi/lo (prescaled) + C bias ----
    f16x8 ahi[5], alo[5];
    f32x4 cb[5];
    bool  l1p[5];
    #pragma unroll
    for (int T = 0; T < 5; ++T) {
        const int Pa = 4 * T + (e >> 2), Ga = e & 3;
        const int La = (Pa >= 10);
        const int Ua = Pa - La * 10;
        const int wr = Ga * 10 + Ua;
        const float m = (Ga == 2) ? LOG2E2 : -LOG2E;
        #pragma unroll
        for (int j = 0; j < 8; ++j) {
            const int k = q * 8 + j;
            float w = 0.0f;
            if (k < 2) {                               // x_hi (q0, j<2)
                w = La ? 0.0f : w_ih0[wr * 2 + k];
            } else if (j >= 2 && j <= 6) {             // h pair p=4*(j-2)+q
                const int p = 4 * (j - 2) + q;
                if (p < 10) w = La ? w_ih1[wr * 10 + p] : w_hh0[wr * 10 + p];
                else        w = La ? w_hh1[wr * 10 + (p - 10)] : 0.0f;
            } else if (j == 7) {                       // x_lo dup cols
                if (q == 0)      w = La ? 0.0f : w_ih0[wr * 2 + 0];
                else if (q == 1) w = La ? 0.0f : w_ih0[wr * 2 + 1];
            }
            const float wm = m * w;
            const _Float16 wh = (_Float16)wm;
            ahi[T][j] = wh;
            alo[T][j] = (_Float16)(wm - (float)wh);
        }
        const int Pc = 4 * T + q;
        l1p[T] = (Pc >= 10);
        const int Lc = (Pc >= 10);
        const int Uc = Pc - Lc * 10;
        #pragma unroll
        for (int r = 0; r < 4; ++r) {
            const int wrc = r * 10 + Uc;
            const float mc = (r == 2) ? LOG2E2 : -LOG2E;
            cb[T][r] = mc * (Lc ? (b_ih1[wrc] + b_hh1[wrc])
                                : (b_ih0[wrc] + b_hh0[wrc]));
        }
    }

    // ---- per-group x base pointers ----
    const float* xeA = x + ((size_t)Eb + e) * 2;
    const float* xeB = x + ((size_t)Eb + 16 + e) * 2;

    // PKX: float2 -> (bd0 dword, x_lo f16 half), lane-selected
#define PKX(V, UX, UT)                                                         \
    {                                                                          \
        const _Float16 ha = (_Float16)(V).x, hb = (_Float16)(V).y;             \
        (UX) = qz ? pkf16(ha, hb) : 0u;                                        \
        const _Float16 la = (_Float16)((V).x - (float)ha);                     \
        const _Float16 lb = (_Float16)((V).y - (float)hb);                     \
        (UT) = qz ? la : ((q == 1) ? lb : (_Float16)0.f);                      \
    }

    unsigned ux0A, ux1A, ux0B, ux1B; _Float16 ut0A, ut1A, ut0B, ut1B;
    {
        const float2 vA0 = *(const float2*)xeA;
        const float2 vA1 = *(const float2*)(xeA + (size_t)1 * BATCH * 2);
        const float2 vB0 = *(const float2*)xeB;
        const float2 vB1 = *(const float2*)(xeB + (size_t)1 * BATCH * 2);
        PKX(vA0, ux0A, ut0A) PKX(vA1, ux1A, ut1A)
        PKX(vB0, ux0B, ut0B) PKX(vB1, ux1B, ut1B)
    }
    unsigned uxFA[8], uxSA[8], uxFB[8], uxSB[8];
    _Float16 utFA[8], utSA[8], utFB[8], utSB[8];
    #pragma unroll
    for (int i = 0; i < 8; ++i) {
        const float2 vA = *(const float2*)(xeA + (size_t)(2 + i) * BATCH * 2);
        const float2 vB = *(const float2*)(xeB + (size_t)(2 + i) * BATCH * 2);
        PKX(vA, uxFA[i], utFA[i]) PKX(vB, uxFB[i], utFB[i])
    }
    #pragma unroll
    for (int i = 0; i < 8; ++i) {
        const float2 vA = *(const float2*)(xeA + (size_t)(10 + i) * BATCH * 2);
        const float2 vB = *(const float2*)(xeB + (size_t)(10 + i) * BATCH * 2);
        PKX(vA, uxSA[i], utSA[i]) PKX(vB, uxSB[i], utSB[i])
    }

    // ---- per-group B state (hi dwords) ----
    unsigned bdA0 = ux0A, bdA1 = 0u, bdA2 = 0u, bdA3 = pkf16((_Float16)0.f, ut0A);
    unsigned bdB0 = ux0B, bdB1 = 0u, bdB2 = 0u, bdB3 = pkf16((_Float16)0.f, ut0B);

    float cstA[5] = {0.f, 0.f, 0.f, 0.f, 0.f};
    float cstB[5] = {0.f, 0.f, 0.f, 0.f, 0.f};
    float hTA[5], hTB[5];

    // gate stage for tile T of one group
#define ACTG(T, ZZ, SUP, CST, EC, SO)                                          \
    {                                                                          \
        const float a0 = 1.0f + fexp2(ZZ[0]);                                  \
        const float a1 = 1.0f + fexp2(ZZ[1]);                                  \
        const float a2 = 1.0f + fexp2(ZZ[2]);                                  \
        const float a3 = 1.0f + fexp2(ZZ[3]);                                  \
        const float m1 = a0 * a1, m2 = a2 * a3;                                \
        const float pq_ = frcp(m1 * m2);                                       \
        const float pif = m2 * pq_, pgo = m1 * pq_;                            \
        const float si = a1 * pif, sf = a0 * pif;                              \
        const float tg = fmaf(-2.0f, a3 * pgo, 1.0f);                          \
        SO[T] = a2 * pgo;                                                      \
        float cn = fmaf(sf, CST[T], si * tg);                                  \
        if (SUP) cn = l1p[T] ? 0.0f : cn;                                      \
        CST[T] = cn;                                                           \
        EC[T] = 1.0f + fexp2(LOG2E2 * cn);                                     \
    }

    // dual step: both groups' MFMAs first (B's issue under A's latency),
    // then both activations (two concurrent trans chains), then repacks.
#define STEPDUO(UXA, UTA, UXB, UTB, SUP)                                       \
    {                                                                          \
        const f16x8 BvA = __builtin_bit_cast(f16x8, (u32x4){bdA0, bdA1, bdA2, bdA3}); \
        const f16x8 BvB = __builtin_bit_cast(f16x8, (u32x4){bdB0, bdB1, bdB2, bdB3}); \
        f32x4 zA0 = __builtin_amdgcn_mfma_f32_16x16x32_f16(ahi[0], BvA, cb[0], 0, 0, 0); \
        f32x4 zA1 = __builtin_amdgcn_mfma_f32_16x16x32_f16(ahi[1], BvA, cb[1], 0, 0, 0); \
        f32x4 zA2 = __builtin_amdgcn_mfma_f32_16x16x32_f16(ahi[2], BvA, cb[2], 0, 0, 0); \
        f32x4 zA3 = __builtin_amdgcn_mfma_f32_16x16x32_f16(ahi[3], BvA, cb[3], 0, 0, 0); \
        f32x4 zA4 = __builtin_amdgcn_mfma_f32_16x16x32_f16(ahi[4], BvA, cb[4], 0, 0, 0); \
        f32x4 zB0 = __builtin_amdgcn_mfma_f32_16x16x32_f16(ahi[0], BvB, cb[0], 0, 0, 0); \
        f32x4 zB1 = __builtin_amdgcn_mfma_f32_16x16x32_f16(ahi[1], BvB, cb[1], 0, 0, 0); \
        f32x4 zB2 = __builtin_amdgcn_mfma_f32_16x16x32_f16(ahi[2], BvB, cb[2], 0, 0, 0); \
        f32x4 zB3 = __builtin_amdgcn_mfma_f32_16x16x32_f16(ahi[3], BvB, cb[3], 0, 0, 0); \
        f32x4 zB4 = __builtin_amdgcn_mfma_f32_16x16x32_f16(ahi[4], BvB, cb[4], 0, 0, 0); \
        zA0 = __builtin_amdgcn_mfma_f32_16x16x32_f16(alo[0], BvA, zA0, 0, 0, 0); \
        zA1 = __builtin_amdgcn_mfma_f32_16x16x32_f16(alo[1], BvA, zA1, 0, 0, 0); \
        zA2 = __builtin_amdgcn_mfma_f32_16x16x32_f16(alo[2], BvA, zA2, 0, 0, 0); \
        zA3 = __builtin_amdgcn_mfma_f32_16x16x32_f16(alo[3], BvA, zA3, 0, 0, 0); \
        zA4 = __builtin_amdgcn_mfma_f32_16x16x32_f16(alo[4], BvA, zA4, 0, 0, 0); \
        zB0 = __builtin_amdgcn_mfma_f32_16x16x32_f16(alo[0], BvB, zB0, 0, 0, 0); \
        zB1 = __builtin_amdgcn_mfma_f32_16x16x32_f16(alo[1], BvB, zB1, 0, 0, 0); \
        zB2 = __builtin_amdgcn_mfma_f32_16x16x32_f16(alo[2], BvB, zB2, 0, 0, 0); \
        zB3 = __builtin_amdgcn_mfma_f32_16x16x32_f16(alo[3], BvB, zB3, 0, 0, 0); \
        zB4 = __builtin_amdgcn_mfma_f32_16x16x32_f16(alo[4], BvB, zB4, 0, 0, 0); \
        float eCA[5], sOA[5], eCB[5], sOB[5];                                  \
        ACTG(0, zA0, SUP, cstA, eCA, sOA) ACTG(1, zA1, SUP, cstA, eCA, sOA)    \
        ACTG(2, zA2, SUP, cstA, eCA, sOA) ACTG(3, zA3, SUP, cstA, eCA, sOA)    \
        ACTG(4, zA4, SUP, cstA, eCA, sOA)                                      \
        ACTG(0, zB0, SUP, cstB, eCB, sOB) ACTG(1, zB1, SUP, cstB, eCB, sOB)    \
        ACTG(2, zB2, SUP, cstB, eCB, sOB) ACTG(3, zB3, SUP, cstB, eCB, sOB)    \
        ACTG(4, zB4, SUP, cstB, eCB, sOB)                                      \
        const float pA01 = frcp(eCA[0] * eCA[1]);                              \
        const float pA23 = frcp(eCA[2] * eCA[3]);                              \
        const float pA4  = frcp(eCA[4]);                                       \
        const float pB01 = frcp(eCB[0] * eCB[1]);                              \
        const float pB23 = frcp(eCB[2] * eCB[3]);                              \
        const float pB4  = frcp(eCB[4]);                                       \
        hTA[0] = sOA[0] * fmaf(-2.0f, eCA[1] * pA01, 1.0f);                    \
        hTA[1] = sOA[1] * fmaf(-2.0f, eCA[0] * pA01, 1.0f);                    \
        hTA[2] = sOA[2] * fmaf(-2.0f, eCA[3] * pA23, 1.0f);                    \
        hTA[3] = sOA[3] * fmaf(-2.0f, eCA[2] * pA23, 1.0f);                    \
        hTA[4] = sOA[4] * fmaf(-2.0f, pA4, 1.0f);                              \
        hTB[0] = sOB[0] * fmaf(-2.0f, eCB[1] * pB01, 1.0f);                    \
        hTB[1] = sOB[1] * fmaf(-2.0f, eCB[0] * pB01, 1.0f);                    \
        hTB[2] = sOB[2] * fmaf(-2.0f, eCB[3] * pB23, 1.0f);                    \
        hTB[3] = sOB[3] * fmaf(-2.0f, eCB[2] * pB23, 1.0f);                    \
        hTB[4] = sOB[4] * fmaf(-2.0f, pB4, 1.0f);                              \
        bdA1 = pkf16((_Float16)hTA[0], (_Float16)hTA[1]);                      \
        bdA2 = pkf16((_Float16)hTA[2], (_Float16)hTA[3]);                      \
        bdA3 = pkf16((_Float16)hTA[4], (UTA));                                 \
        bdA0 = (UXA);                                                          \
        bdB1 = pkf16((_Float16)hTB[0], (_Float16)hTB[1]);                      \
        bdB2 = pkf16((_Float16)hTB[2], (_Float16)hTB[3]);                      \
        bdB3 = pkf16((_Float16)hTB[4], (UTB));                                 \
        bdB0 = (UXB);                                                          \
    }

    // prologue (t=-1): v=[x0,0,0] -> h1[0]; L1 pairs suppressed; insert x[1]
    STEPDUO(ux1A, ut1A, ux1B, ut1B, 1)

    // main: 32 iters x 16 steps = 512
    for (int cc = 0; cc < 32; ++cc) {
        #pragma unroll
        for (int s = 0; s < 8; ++s) STEPDUO(uxFA[s], utFA[s], uxFB[s], utFB[s], 0)
        #pragma unroll
        for (int i = 0; i < 8; ++i) {
            int ti = 16 * cc + 18 + i; if (ti > 511) ti = 511;
            const float2 vA = *(const float2*)(xeA + (size_t)ti * BATCH * 2);
            const float2 vB = *(const float2*)(xeB + (size_t)ti * BATCH * 2);
            PKX(vA, uxFA[i], utFA[i]) PKX(vB, uxFB[i], utFB[i])
        }
        #pragma unroll
        for (int s = 0; s < 8; ++s) STEPDUO(uxSA[s], utSA[s], uxSB[s], utSB[s], 0)
        #pragma unroll
        for (int i = 0; i < 8; ++i) {
            int ti = 16 * cc + 26 + i; if (ti > 511) ti = 511;
            const float2 vA = *(const float2*)(xeA + (size_t)ti * BATCH * 2);
            const float2 vB = *(const float2*)(xeB + (size_t)ti * BATCH * 2);
            PKX(vA, uxSA[i], utSA[i]) PKX(vB, uxSB[i], utSB[i])
        }
    }
#undef STEPDUO
#undef ACTG
#undef PKX

    // ---- FC: L1 pairs of step 511 hold h2[511]; rows 0-15 = A, 16-31 = B ----
    if (q >= 2) { hfc[e][q - 2] = hTA[2]; hfc[16 + e][q - 2] = hTB[2]; }
    hfc[e][2 + q]      = hTA[3];  hfc[16 + e][2 + q] = hTB[3];
    hfc[e][6 + q]      = hTA[4];  hfc[16 + e][6 + q] = hTB[4];
    __syncthreads();
    {
        const int ee = lane >> 1, jj = lane & 1;      // all 64 lanes used
        float acc = fc_b[jj];
        #pragma unroll
        for (int u = 0; u < 10; ++u)
            acc = fmaf(fc_w[jj * 10 + u], hfc[ee][u], acc);
        out[((size_t)Eb + ee) * 2 + jj] = acc;
    }
}

extern "C" void kernel_launch(void* const* d_in, const int* in_sizes, int n_in,
                              void* d_out, int out_size, void* d_ws, size_t ws_size,
                              hipStream_t stream) {
    const float* x     = (const float*)d_in[0];
    const float* w_ih0 = (const float*)d_in[1];
    const float* w_hh0 = (const float*)d_in[2];
    const float* b_ih0 = (const float*)d_in[3];
    const float* b_hh0 = (const float*)d_in[4];
    const float* w_ih1 = (const float*)d_in[5];
    const float* w_hh1 = (const float*)d_in[6];
    const float* b_ih1 = (const float*)d_in[7];
    const float* b_hh1 = (const float*)d_in[8];
    const float* fc_w  = (const float*)d_in[9];
    const float* fc_b  = (const float*)d_in[10];
    float* out = (float*)d_out;

    const int threads = 64;                   // 1 wave = 2 x 16 batch elements
    const int blocks  = BATCH / 32;           // 256 waves, 1 per CU
    lstm2_fc_mfma<<<blocks, threads, 0, stream>>>(
        x, w_ih0, w_hh0, b_ih0, b_hh0,
        w_ih1, w_hh1, b_ih1, b_hh1, fc_w, fc_b, out);
}

// Round 15
// 407.203 us; speedup vs baseline: 1.1657x; 1.1657x over previous
//
#include <hip/hip_runtime.h>

#define SEQ 512
#define BATCH 8192
#define LOG2E  1.44269504088896340736f
#define LOG2E2 2.88539008177792681472f   // 2*log2(e)

typedef _Float16 f16x8 __attribute__((ext_vector_type(8)));
typedef float    f32x4 __attribute__((ext_vector_type(4)));

__device__ __forceinline__ float fexp2(float x) { return __builtin_amdgcn_exp2f(x); }
__device__ __forceinline__ float frcp(float x)  { return __builtin_amdgcn_rcpf(x); }

// MFMA LSTM, all-register recurrence (r9 = 227us champion), repacked into
// 8-wave blocks so the HW scheduler co-locates 2 waves per SIMD.
// r14 proved in-wave dual-chaining gains nothing (compiler/static schedule
// can't fill stalls); this uses DYNAMIC cross-wave interleave instead:
// 64 blocks x 512 threads -> 8 independent 16-element waves per CU ->
// 2 waves/SIMD; wave B's issue fills wave A's dependency stalls.
// Per-wave math is r9 verbatim (verified absmax 6.1e-5):
//   step t: z(80) = W(80x22-perm)·v, v=[x[t+1]; h1[t]; h2[t-1]], 5 tiles x
//   3 chained mfma_f32_16x16x32_f16 (W_hi·v_hi + W_lo·v_hi + W_hi·v_lo + b).
//   Pair P=4T+q at k=8q+(2+T); D gives lane (q,e) pairs {4T+q} ->
//   producer lane == consumer lane; recurrence never leaves registers.
__global__ __launch_bounds__(512, 2) void lstm2_fc_mfma(
    const float* __restrict__ x,
    const float* __restrict__ w_ih0, const float* __restrict__ w_hh0,
    const float* __restrict__ b_ih0, const float* __restrict__ b_hh0,
    const float* __restrict__ w_ih1, const float* __restrict__ w_hh1,
    const float* __restrict__ b_ih1, const float* __restrict__ b_hh1,
    const float* __restrict__ fc_w, const float* __restrict__ fc_b,
    float* __restrict__ out)
{
    __shared__ float hfc[8][16][10];

    const int tid  = threadIdx.x;
    const int grp  = tid >> 6;       // wave index within block (0..7)
    const int lane = tid & 63;
    const int e    = lane & 15;      // elem column / A-row-in-tile
    const int q    = lane >> 4;      // K-chunk for A/B; row-quad for C/D
    const int Eb   = blockIdx.x * 128 + grp * 16;
    const bool qz  = (q == 0);

    // ---- A fragments hi/lo (prescaled) + C bias ----
    f16x8 ahi[5], alo[5];
    f32x4 cb[5];
    bool  l1p[5];
    #pragma unroll
    for (int T = 0; T < 5; ++T) {
        const int Pa = 4 * T + (e >> 2), Ga = e & 3;   // A row e -> pair/gate
        const int La = (Pa >= 10);
        const int Ua = Pa - La * 10;
        const int wr = Ga * 10 + Ua;                   // torch row in 40-block
        const float m = (Ga == 2) ? LOG2E2 : -LOG2E;
        #pragma unroll
        for (int j = 0; j < 8; ++j) {
            const int k = q * 8 + j;
            float w = 0.0f;
            if (k < 2) {                               // x slots (q==0, j<2)
                w = La ? 0.0f : w_ih0[wr * 2 + k];
            } else if (j >= 2 && j <= 6) {             // pair p = 4*(j-2)+q
                const int p = 4 * (j - 2) + q;
                if (p < 10) w = La ? w_ih1[wr * 10 + p] : w_hh0[wr * 10 + p];
                else        w = La ? w_hh1[wr * 10 + (p - 10)] : 0.0f;
            }
            const float wm = m * w;
            const _Float16 wh = (_Float16)wm;
            ahi[T][j] = wh;
            alo[T][j] = (_Float16)(wm - (float)wh);
        }
        const int Pc = 4 * T + q;                      // C/D pair for this lane
        l1p[T] = (Pc >= 10);
        const int Lc = (Pc >= 10);
        const int Uc = Pc - Lc * 10;
        #pragma unroll
        for (int r = 0; r < 4; ++r) {
            const int wrc = r * 10 + Uc;
            const float mc = (r == 2) ? LOG2E2 : -LOG2E;
            cb[T][r] = mc * (Lc ? (b_ih1[wrc] + b_hh1[wrc])
                                : (b_ih0[wrc] + b_hh0[wrc]));
        }
    }

    // ---- B state registers ----
    f16x8 bh, bl;
    #pragma unroll
    for (int j = 0; j < 8; ++j) { bh[j] = (_Float16)0.f; bl[j] = (_Float16)0.f; }

    // ---- x prefetch: x[0], x[1], then 8-step chunks ----
    const float* xe = x + ((size_t)Eb + e) * 2;
    const float2 x0 = *(const float2*)xe;
    const float2 x1 = *(const float2*)(xe + (size_t)1 * BATCH * 2);
    float2 xr0[8], xr1[8];
    #pragma unroll
    for (int i = 0; i < 8; ++i) xr0[i] = *(const float2*)(xe + (size_t)(2 + i) * BATCH * 2);
    #pragma unroll
    for (int i = 0; i < 8; ++i) xr1[i] = *(const float2*)(xe + (size_t)(10 + i) * BATCH * 2);

    // insert x[0] into B (q==0 lanes; others keep 0)
    {
        const _Float16 xa = (_Float16)x0.x, xb2 = (_Float16)x0.y;
        bh[0] = qz ? xa : (_Float16)0.f;
        bh[1] = qz ? xb2 : (_Float16)0.f;
        bl[0] = qz ? (_Float16)(x0.x - (float)xa) : (_Float16)0.f;
        bl[1] = qz ? (_Float16)(x0.y - (float)xb2) : (_Float16)0.f;
    }

    float cst[5] = {0.f, 0.f, 0.f, 0.f, 0.f};
    float hT[5];

#define ACT(T, ZZ, SUP)                                                        \
    {                                                                          \
        const float d0 = 1.0f + fexp2(ZZ[0]);                                  \
        const float d1 = 1.0f + fexp2(ZZ[1]);                                  \
        const float d2 = 1.0f + fexp2(ZZ[2]);                                  \
        const float d3 = 1.0f + fexp2(ZZ[3]);                                  \
        const float m1 = d0 * d1, m2 = d2 * d3;                                \
        const float pq_ = frcp(m1 * m2);                                       \
        const float pif = m2 * pq_, pgo = m1 * pq_;                            \
        const float si = d1 * pif, sf = d0 * pif;                              \
        const float tg = fmaf(-2.0f, d3 * pgo, 1.0f);                          \
        sO[T] = d2 * pgo;                                                      \
        float cn = fmaf(sf, cst[T], si * tg);                                  \
        if (SUP) cn = l1p[T] ? 0.0f : cn;  /* prologue: L1 pairs stay 0 */     \
        cst[T] = cn;                                                           \
        eC[T] = 1.0f + fexp2(LOG2E2 * cn);                                     \
    }

    // one pipelined step, all-register: consume bh/bl, update bh/bl in place.
#define STEP(XIN, SUP)                                                         \
    {                                                                          \
        f32x4 z0 = __builtin_amdgcn_mfma_f32_16x16x32_f16(ahi[0], bh, cb[0], 0, 0, 0); \
        f32x4 z1 = __builtin_amdgcn_mfma_f32_16x16x32_f16(ahi[1], bh, cb[1], 0, 0, 0); \
        f32x4 z2 = __builtin_amdgcn_mfma_f32_16x16x32_f16(ahi[2], bh, cb[2], 0, 0, 0); \
        f32x4 z3 = __builtin_amdgcn_mfma_f32_16x16x32_f16(ahi[3], bh, cb[3], 0, 0, 0); \
        f32x4 z4 = __builtin_amdgcn_mfma_f32_16x16x32_f16(ahi[4], bh, cb[4], 0, 0, 0); \
        z0 = __builtin_amdgcn_mfma_f32_16x16x32_f16(alo[0], bh, z0, 0, 0, 0);  \
        z1 = __builtin_amdgcn_mfma_f32_16x16x32_f16(alo[1], bh, z1, 0, 0, 0);  \
        z2 = __builtin_amdgcn_mfma_f32_16x16x32_f16(alo[2], bh, z2, 0, 0, 0);  \
        z3 = __builtin_amdgcn_mfma_f32_16x16x32_f16(alo[3], bh, z3, 0, 0, 0);  \
        z4 = __builtin_amdgcn_mfma_f32_16x16x32_f16(alo[4], bh, z4, 0, 0, 0);  \
        z0 = __builtin_amdgcn_mfma_f32_16x16x32_f16(ahi[0], bl, z0, 0, 0, 0);  \
        z1 = __builtin_amdgcn_mfma_f32_16x16x32_f16(ahi[1], bl, z1, 0, 0, 0);  \
        z2 = __builtin_amdgcn_mfma_f32_16x16x32_f16(ahi[2], bl, z2, 0, 0, 0);  \
        z3 = __builtin_amdgcn_mfma_f32_16x16x32_f16(ahi[3], bl, z3, 0, 0, 0);  \
        z4 = __builtin_amdgcn_mfma_f32_16x16x32_f16(ahi[4], bl, z4, 0, 0, 0);  \
        float eC[5], sO[5];                                                    \
        ACT(0, z0, SUP) ACT(1, z1, SUP) ACT(2, z2, SUP)                        \
        ACT(3, z3, SUP) ACT(4, z4, SUP)                                        \
        const float p01 = frcp(eC[0] * eC[1]);                                 \
        const float p23 = frcp(eC[2] * eC[3]);                                 \
        const float p4  = frcp(eC[4]);                                         \
        hT[0] = sO[0] * fmaf(-2.0f, eC[1] * p01, 1.0f);                        \
        hT[1] = sO[1] * fmaf(-2.0f, eC[0] * p01, 1.0f);                        \
        hT[2] = sO[2] * fmaf(-2.0f, eC[3] * p23, 1.0f);                        \
        hT[3] = sO[3] * fmaf(-2.0f, eC[2] * p23, 1.0f);                        \
        hT[4] = sO[4] * fmaf(-2.0f, p4, 1.0f);                                 \
        _Pragma("unroll")                                                      \
        for (int T = 0; T < 5; ++T) {                                          \
            const _Float16 hh = (_Float16)hT[T];                               \
            bh[2 + T] = hh;                                                    \
            bl[2 + T] = (_Float16)(hT[T] - (float)hh);                         \
        }                                                                      \
        const _Float16 xa = (_Float16)(XIN).x, xb2 = (_Float16)(XIN).y;        \
        bh[0] = qz ? xa : (_Float16)0.f;                                       \
        bh[1] = qz ? xb2 : (_Float16)0.f;                                      \
        bl[0] = qz ? (_Float16)((XIN).x - (float)xa) : (_Float16)0.f;          \
        bl[1] = qz ? (_Float16)((XIN).y - (float)xb2) : (_Float16)0.f;         \
    }

    // prologue (t=-1): v=[x0,0,0] -> h1[0]; L1 pairs suppressed; insert x[1]
    STEP(x1, 1)

    // main: 32 iters x 16 steps = 512 (t = 0..511); step t inserts x[t+2]
    for (int cc = 0; cc < 32; ++cc) {
        #pragma unroll
        for (int s = 0; s < 8; ++s) STEP(xr0[s], 0)        // t=16cc+s
        #pragma unroll
        for (int i = 0; i < 8; ++i) {                      // reload chunk 2cc+2
            int ti = 16 * cc + 18 + i; if (ti > 511) ti = 511;
            xr0[i] = *(const float2*)(xe + (size_t)ti * BATCH * 2);
        }
        #pragma unroll
        for (int s = 0; s < 8; ++s) STEP(xr1[s], 0)        // t=16cc+8+s
        #pragma unroll
        for (int i = 0; i < 8; ++i) {                      // reload chunk 2cc+3
            int ti = 16 * cc + 26 + i; if (ti > 511) ti = 511;
            xr1[i] = *(const float2*)(xe + (size_t)ti * BATCH * 2);
        }
    }
#undef STEP
#undef ACT

    // ---- FC: L1 pairs of step 511 hold h2[511] ----
    if (q >= 2) hfc[grp][e][q - 2] = hT[2];       // pairs 10,11 -> units 0,1
    hfc[grp][e][2 + q] = hT[3];                   // pairs 12..15 -> units 2..5
    hfc[grp][e][6 + q] = hT[4];                   // pairs 16..19 -> units 6..9
    __syncthreads();
    if (lane < 32) {
        const int ee = lane >> 1, jj = lane & 1;
        float acc = fc_b[jj];
        #pragma unroll
        for (int u = 0; u < 10; ++u)
            acc = fmaf(fc_w[jj * 10 + u], hfc[grp][ee][u], acc);
        out[((size_t)Eb + ee) * 2 + jj] = acc;
    }
}

extern "C" void kernel_launch(void* const* d_in, const int* in_sizes, int n_in,
                              void* d_out, int out_size, void* d_ws, size_t ws_size,
                              hipStream_t stream) {
    const float* x     = (const float*)d_in[0];
    const float* w_ih0 = (const float*)d_in[1];
    const float* w_hh0 = (const float*)d_in[2];
    const float* b_ih0 = (const float*)d_in[3];
    const float* b_hh0 = (const float*)d_in[4];
    const float* w_ih1 = (const float*)d_in[5];
    const float* w_hh1 = (const float*)d_in[6];
    const float* b_ih1 = (const float*)d_in[7];
    const float* b_hh1 = (const float*)d_in[8];
    const float* fc_w  = (const float*)d_in[9];
    const float* fc_b  = (const float*)d_in[10];
    float* out = (float*)d_out;

    const int threads = 512;                  // 8 indep waves -> 2 per SIMD
    const int blocks  = BATCH / 128;          // 64 blocks, 64 CUs
    lstm2_fc_mfma<<<blocks, threads, 0, stream>>>(
        x, w_ih0, w_hh0, b_ih0, b_hh0,
        w_ih1, w_hh1, b_ih1, b_hh1, fc_w, fc_b, out);
}

// Round 16
// 218.064 us; speedup vs baseline: 2.1767x; 1.8674x over previous
//
#include <hip/hip_runtime.h>

#define SEQ 512
#define BATCH 8192
#define LOG2E  1.44269504088896340736f
#define LOG2E2 2.88539008177792681472f   // 2*log2(e)

typedef _Float16 f16x8 __attribute__((ext_vector_type(8)));
typedef float    f32x4 __attribute__((ext_vector_type(4)));

__device__ __forceinline__ float fexp2(float x) { return __builtin_amdgcn_exp2f(x); }
__device__ __forceinline__ float frcp(float x)  { return __builtin_amdgcn_rcpf(x); }

// MFMA LSTM, all-register recurrence — r9 champion (227us) with ONE change:
// the third MFMA pass (W_hi·v_lo) is dropped -> 10 MFMA/step, h carried
// hi-f16 only (measured path: absmax 4.88e-4, r11/r13/r14). x stays EXACT:
// x_lo rides in B slot j7 (q0 lanes: x_lo.x, q1 lanes: x_lo.y) against
// duplicated w_ih0 columns in A (A's j7 col is zero for q>=2, so the insert
// needs no mask beyond q<2 selection). All else is r9 verbatim.
//   step t: z(80) = W(80x22-perm)·v, v=[x[t+1]; h1[t]; h2[t-1]],
//   5 tiles x 2 chained mfma_f32_16x16x32_f16 (W_hi·v + W_lo·v + bias).
//   Pair P=4T+q at k=8q+(2+T); D gives lane (q,e) pairs {4T+q} ->
//   producer lane == consumer lane; recurrence never leaves registers.
__global__ __launch_bounds__(64) void lstm2_fc_mfma(
    const float* __restrict__ x,
    const float* __restrict__ w_ih0, const float* __restrict__ w_hh0,
    const float* __restrict__ b_ih0, const float* __restrict__ b_hh0,
    const float* __restrict__ w_ih1, const float* __restrict__ w_hh1,
    const float* __restrict__ b_ih1, const float* __restrict__ b_hh1,
    const float* __restrict__ fc_w, const float* __restrict__ fc_b,
    float* __restrict__ out)
{
    __shared__ float hfc[16][10];

    const int lane = threadIdx.x;
    const int e    = lane & 15;      // elem column / A-row-in-tile
    const int q    = lane >> 4;      // K-chunk for A/B; row-quad for C/D
    const int Eb   = blockIdx.x * 16;
    const bool qz  = (q == 0);

    // ---- A fragments hi/lo (prescaled) + C bias ----
    f16x8 ahi[5], alo[5];
    f32x4 cb[5];
    bool  l1p[5];
    #pragma unroll
    for (int T = 0; T < 5; ++T) {
        const int Pa = 4 * T + (e >> 2), Ga = e & 3;   // A row e -> pair/gate
        const int La = (Pa >= 10);
        const int Ua = Pa - La * 10;
        const int wr = Ga * 10 + Ua;                   // torch row in 40-block
        const float m = (Ga == 2) ? LOG2E2 : -LOG2E;
        #pragma unroll
        for (int j = 0; j < 8; ++j) {
            const int k = q * 8 + j;
            float w = 0.0f;
            if (k < 2) {                               // x_hi slots (q0, j<2)
                w = La ? 0.0f : w_ih0[wr * 2 + k];
            } else if (j >= 2 && j <= 6) {             // h pair p = 4*(j-2)+q
                const int p = 4 * (j - 2) + q;
                if (p < 10) w = La ? w_ih1[wr * 10 + p] : w_hh0[wr * 10 + p];
                else        w = La ? w_hh1[wr * 10 + (p - 10)] : 0.0f;
            } else if (j == 7) {                       // x_lo dup columns
                if (q == 0)      w = La ? 0.0f : w_ih0[wr * 2 + 0];
                else if (q == 1) w = La ? 0.0f : w_ih0[wr * 2 + 1];
            }
            const float wm = m * w;
            const _Float16 wh = (_Float16)wm;
            ahi[T][j] = wh;
            alo[T][j] = (_Float16)(wm - (float)wh);
        }
        const int Pc = 4 * T + q;                      // C/D pair for this lane
        l1p[T] = (Pc >= 10);
        const int Lc = (Pc >= 10);
        const int Uc = Pc - Lc * 10;
        #pragma unroll
        for (int r = 0; r < 4; ++r) {
            const int wrc = r * 10 + Uc;
            const float mc = (r == 2) ? LOG2E2 : -LOG2E;
            cb[T][r] = mc * (Lc ? (b_ih1[wrc] + b_hh1[wrc])
                                : (b_ih0[wrc] + b_hh0[wrc]));
        }
    }

    // ---- B state registers (hi only) ----
    f16x8 bh;
    #pragma unroll
    for (int j = 0; j < 8; ++j) bh[j] = (_Float16)0.f;

    // ---- x prefetch: x[0], x[1], then 8-step chunks ----
    const float* xe = x + ((size_t)Eb + e) * 2;
    const float2 x0 = *(const float2*)xe;
    const float2 x1 = *(const float2*)(xe + (size_t)1 * BATCH * 2);
    float2 xr0[8], xr1[8];
    #pragma unroll
    for (int i = 0; i < 8; ++i) xr0[i] = *(const float2*)(xe + (size_t)(2 + i) * BATCH * 2);
    #pragma unroll
    for (int i = 0; i < 8; ++i) xr1[i] = *(const float2*)(xe + (size_t)(10 + i) * BATCH * 2);

    // insert x[0] into B (q==0 lanes hold x_hi; j7 holds x_lo on q0/q1)
    {
        const _Float16 xa = (_Float16)x0.x, xb2 = (_Float16)x0.y;
        bh[0] = qz ? xa : (_Float16)0.f;
        bh[1] = qz ? xb2 : (_Float16)0.f;
        const _Float16 lx = (_Float16)(x0.x - (float)xa);
        const _Float16 ly = (_Float16)(x0.y - (float)xb2);
        bh[7] = qz ? lx : ly;          // only q0/q1 columns are nonzero in A
    }

    float cst[5] = {0.f, 0.f, 0.f, 0.f, 0.f};
    float hT[5];

#define ACT(T, ZZ, SUP)                                                        \
    {                                                                          \
        const float d0 = 1.0f + fexp2(ZZ[0]);                                  \
        const float d1 = 1.0f + fexp2(ZZ[1]);                                  \
        const float d2 = 1.0f + fexp2(ZZ[2]);                                  \
        const float d3 = 1.0f + fexp2(ZZ[3]);                                  \
        const float m1 = d0 * d1, m2 = d2 * d3;                                \
        const float pq_ = frcp(m1 * m2);                                       \
        const float pif = m2 * pq_, pgo = m1 * pq_;                            \
        const float si = d1 * pif, sf = d0 * pif;                              \
        const float tg = fmaf(-2.0f, d3 * pgo, 1.0f);                          \
        sO[T] = d2 * pgo;                                                      \
        float cn = fmaf(sf, cst[T], si * tg);                                  \
        if (SUP) cn = l1p[T] ? 0.0f : cn;  /* prologue: L1 pairs stay 0 */     \
        cst[T] = cn;                                                           \
        eC[T] = 1.0f + fexp2(LOG2E2 * cn);                                     \
    }

    // one pipelined step, all-register: consume bh, update bh in place.
#define STEP(XIN, SUP)                                                         \
    {                                                                          \
        f32x4 z0 = __builtin_amdgcn_mfma_f32_16x16x32_f16(ahi[0], bh, cb[0], 0, 0, 0); \
        f32x4 z1 = __builtin_amdgcn_mfma_f32_16x16x32_f16(ahi[1], bh, cb[1], 0, 0, 0); \
        f32x4 z2 = __builtin_amdgcn_mfma_f32_16x16x32_f16(ahi[2], bh, cb[2], 0, 0, 0); \
        f32x4 z3 = __builtin_amdgcn_mfma_f32_16x16x32_f16(ahi[3], bh, cb[3], 0, 0, 0); \
        f32x4 z4 = __builtin_amdgcn_mfma_f32_16x16x32_f16(ahi[4], bh, cb[4], 0, 0, 0); \
        z0 = __builtin_amdgcn_mfma_f32_16x16x32_f16(alo[0], bh, z0, 0, 0, 0);  \
        z1 = __builtin_amdgcn_mfma_f32_16x16x32_f16(alo[1], bh, z1, 0, 0, 0);  \
        z2 = __builtin_amdgcn_mfma_f32_16x16x32_f16(alo[2], bh, z2, 0, 0, 0);  \
        z3 = __builtin_amdgcn_mfma_f32_16x16x32_f16(alo[3], bh, z3, 0, 0, 0);  \
        z4 = __builtin_amdgcn_mfma_f32_16x16x32_f16(alo[4], bh, z4, 0, 0, 0);  \
        float eC[5], sO[5];                                                    \
        ACT(0, z0, SUP) ACT(1, z1, SUP) ACT(2, z2, SUP)                        \
        ACT(3, z3, SUP) ACT(4, z4, SUP)                                        \
        const float p01 = frcp(eC[0] * eC[1]);                                 \
        const float p23 = frcp(eC[2] * eC[3]);                                 \
        const float p4  = frcp(eC[4]);                                         \
        hT[0] = sO[0] * fmaf(-2.0f, eC[1] * p01, 1.0f);                        \
        hT[1] = sO[1] * fmaf(-2.0f, eC[0] * p01, 1.0f);                        \
        hT[2] = sO[2] * fmaf(-2.0f, eC[3] * p23, 1.0f);                        \
        hT[3] = sO[3] * fmaf(-2.0f, eC[2] * p23, 1.0f);                        \
        hT[4] = sO[4] * fmaf(-2.0f, p4, 1.0f);                                 \
        _Pragma("unroll")                                                      \
        for (int T = 0; T < 5; ++T) bh[2 + T] = (_Float16)hT[T];               \
        const _Float16 xa = (_Float16)(XIN).x, xb2 = (_Float16)(XIN).y;        \
        bh[0] = qz ? xa : (_Float16)0.f;                                       \
        bh[1] = qz ? xb2 : (_Float16)0.f;                                      \
        const _Float16 lx = (_Float16)((XIN).x - (float)xa);                   \
        const _Float16 ly = (_Float16)((XIN).y - (float)xb2);                  \
        bh[7] = qz ? lx : ly;                                                  \
    }

    // prologue (t=-1): v=[x0,0,0] -> h1[0]; L1 pairs suppressed; insert x[1]
    STEP(x1, 1)

    // main: 32 iters x 16 steps = 512 (t = 0..511); step t inserts x[t+2]
    for (int cc = 0; cc < 32; ++cc) {
        #pragma unroll
        for (int s = 0; s < 8; ++s) STEP(xr0[s], 0)        // t=16cc+s
        #pragma unroll
        for (int i = 0; i < 8; ++i) {                      // reload chunk 2cc+2
            int ti = 16 * cc + 18 + i; if (ti > 511) ti = 511;
            xr0[i] = *(const float2*)(xe + (size_t)ti * BATCH * 2);
        }
        #pragma unroll
        for (int s = 0; s < 8; ++s) STEP(xr1[s], 0)        // t=16cc+8+s
        #pragma unroll
        for (int i = 0; i < 8; ++i) {                      // reload chunk 2cc+3
            int ti = 16 * cc + 26 + i; if (ti > 511) ti = 511;
            xr1[i] = *(const float2*)(xe + (size_t)ti * BATCH * 2);
        }
    }
#undef STEP
#undef ACT

    // ---- FC: L1 pairs of step 511 hold h2[511] ----
    if (q >= 2) hfc[e][q - 2] = hT[2];            // pairs 10,11 -> units 0,1
    hfc[e][2 + q] = hT[3];                        // pairs 12..15 -> units 2..5
    hfc[e][6 + q] = hT[4];                        // pairs 16..19 -> units 6..9
    __syncthreads();
    if (lane < 32) {
        const int ee = lane >> 1, jj = lane & 1;
        float acc = fc_b[jj];
        #pragma unroll
        for (int u = 0; u < 10; ++u)
            acc = fmaf(fc_w[jj * 10 + u], hfc[ee][u], acc);
        out[((size_t)Eb + ee) * 2 + jj] = acc;
    }
}

extern "C" void kernel_launch(void* const* d_in, const int* in_sizes, int n_in,
                              void* d_out, int out_size, void* d_ws, size_t ws_size,
                              hipStream_t stream) {
    const float* x     = (const float*)d_in[0];
    const float* w_ih0 = (const float*)d_in[1];
    const float* w_hh0 = (const float*)d_in[2];
    const float* b_ih0 = (const float*)d_in[3];
    const float* b_hh0 = (const float*)d_in[4];
    const float* w_ih1 = (const float*)d_in[5];
    const float* w_hh1 = (const float*)d_in[6];
    const float* b_ih1 = (const float*)d_in[7];
    const float* b_hh1 = (const float*)d_in[8];
    const float* fc_w  = (const float*)d_in[9];
    const float* fc_b  = (const float*)d_in[10];
    float* out = (float*)d_out;

    const int threads = 64;                   // 1 wave = 16 batch elements
    const int blocks  = BATCH / 16;           // 512 waves
    lstm2_fc_mfma<<<blocks, threads, 0, stream>>>(
        x, w_ih0, w_hh0, b_ih0, b_hh0,
        w_ih1, w_hh1, b_ih1, b_hh1, fc_w, fc_b, out);
}